// Round 6
// baseline (154.870 us; speedup 1.0000x reference)
//
#include <hip/hip_runtime.h>

// TSM temporal shift: x (B_T=128, C=256, H=56, W=56) fp32, num_segments=8, fold_div=3.
// B=16, T=8, fold=85. Flat index i = ((b*T + t)*C + c)*HW + hw.
// out[c <  fold]      = (t < T-1) ? in[i + CHW] : 0
// out[fold<=c<2fold]  = (t > 0)   ? in[i - CHW] : 0
// out[c >= 2fold]     = in[i]
// f32x4-vectorized (HW=3136 % 4 == 0; (c,t) constant within an f32x4).
// R4: 1792 blocks x 7 chunks (perfect balance), unroll 8, branchless. 141 us.
// R5: 2-deep reg-double-buffered pipeline (loads of k+1 before stores of k). 139 us.
// R6 A/B: REMOVE nontemporal hints (never isolated; fastest references on this
//         chip — 6.85 TB/s fill, 6.29 TB/s m13 copy — use plain loads/stores).

namespace {
typedef float f32x4 __attribute__((ext_vector_type(4)));

constexpr int kT    = 8;
constexpr int kC    = 256;
constexpr int kHW4  = (56 * 56) / 4;       // 784
constexpr int kCHW4 = kC * kHW4;           // 200704 (f32x4 units)
constexpr int kFold = kC / 3;              // 85
constexpr int kN4   = 128 * kC * kHW4;     // 25,690,112 f32x4 elements
constexpr int kBlk  = 256;
constexpr int kUnroll = 8;
constexpr int kChunk  = kBlk * kUnroll;    // 2048; kN4 % 2048 == 0
constexpr int kNChunks = kN4 / kChunk;     // 12544 = 1792 * 7 exactly
constexpr int kGrid  = 1792;               // 7 blocks/CU, perfectly balanced
constexpr int kSteps = kNChunks / kGrid;   // 7 chunks per block
constexpr int kStride = kGrid * kChunk;    // 3,670,016 f32x4 between chunks
}

__device__ __forceinline__ void load_chunk(f32x4* v, int base,
                                           const f32x4* __restrict__ in) {
  const f32x4 zero = {0.f, 0.f, 0.f, 0.f};
#pragma unroll
  for (int j = 0; j < kUnroll; ++j) {
    const int i = base + j * kBlk;
    const int plane = i / kHW4;            // magic-mul div
    const int c = plane & (kC - 1);        // C=256 pow2
    const int t = (plane >> 8) & (kT - 1); // T=8 pow2
    int off;
    bool valid;
    if (c < kFold)          { off =  kCHW4; valid = (t < kT - 1); }
    else if (c < 2 * kFold) { off = -kCHW4; valid = (t > 0); }
    else                    { off = 0;      valid = true; }
    v[j] = valid ? in[i + off] : zero;
  }
}

__device__ __forceinline__ void store_chunk(const f32x4* v, int base,
                                            f32x4* __restrict__ out) {
#pragma unroll
  for (int j = 0; j < kUnroll; ++j)
    out[base + j * kBlk] = v[j];
}

__global__ __launch_bounds__(kBlk) void tsm_shift_kernel(
    const f32x4* __restrict__ in, f32x4* __restrict__ out) {
  f32x4 A[kUnroll], B[kUnroll];
  int base = blockIdx.x * kChunk + (int)threadIdx.x;
  load_chunk(A, base, in);
#pragma unroll
  for (int k = 0; k < kSteps; ++k) {
    f32x4* cur = (k & 1) ? B : A;   // static after unroll -> stays in registers
    f32x4* nxt = (k & 1) ? A : B;
    if (k + 1 < kSteps) load_chunk(nxt, base + kStride, in);
    store_chunk(cur, base, out);
    base += kStride;
  }
}

extern "C" void kernel_launch(void* const* d_in, const int* in_sizes, int n_in,
                              void* d_out, int out_size, void* d_ws, size_t ws_size,
                              hipStream_t stream) {
  const f32x4* x = (const f32x4*)d_in[0];
  f32x4* out = (f32x4*)d_out;
  tsm_shift_kernel<<<kGrid, kBlk, 0, stream>>>(x, out);
}

// Round 7
// 138.982 us; speedup vs baseline: 1.1143x; 1.1143x over previous
//
#include <hip/hip_runtime.h>

// TSM temporal shift: x (B_T=128, C=256, H=56, W=56) fp32, num_segments=8, fold_div=3.
// B=16, T=8, fold=85. Flat index i = ((b*T + t)*C + c)*HW + hw.
// out[c <  fold]      = (t < T-1) ? in[i + CHW] : 0
// out[fold<=c<2fold]  = (t > 0)   ? in[i - CHW] : 0
// out[c >= 2fold]     = in[i]
// f32x4-vectorized (HW=3136 % 4 == 0; (c,t) constant within an f32x4).
// R4: 1792 blocks x 7 chunks (perfect balance), unroll 8, branchless. 141 us.
// R5: 2-deep reg-double-buffered pipeline + nontemporal. 139 us  <-- best
// R6: A/B removed nt -> 155 us (nt helps ~11%; single-touch lines, no reuse).
// R7: restore R5 (best known). At 5.67 TB/s = 90% of m13 copy ceiling.

namespace {
typedef float f32x4 __attribute__((ext_vector_type(4)));

constexpr int kT    = 8;
constexpr int kC    = 256;
constexpr int kHW4  = (56 * 56) / 4;       // 784
constexpr int kCHW4 = kC * kHW4;           // 200704 (f32x4 units)
constexpr int kFold = kC / 3;              // 85
constexpr int kN4   = 128 * kC * kHW4;     // 25,690,112 f32x4 elements
constexpr int kBlk  = 256;
constexpr int kUnroll = 8;
constexpr int kChunk  = kBlk * kUnroll;    // 2048; kN4 % 2048 == 0
constexpr int kNChunks = kN4 / kChunk;     // 12544 = 1792 * 7 exactly
constexpr int kGrid  = 1792;               // 7 blocks/CU, perfectly balanced
constexpr int kSteps = kNChunks / kGrid;   // 7 chunks per block
constexpr int kStride = kGrid * kChunk;    // 3,670,016 f32x4 between chunks
}

__device__ __forceinline__ void load_chunk(f32x4* v, int base,
                                           const f32x4* __restrict__ in) {
  const f32x4 zero = {0.f, 0.f, 0.f, 0.f};
#pragma unroll
  for (int j = 0; j < kUnroll; ++j) {
    const int i = base + j * kBlk;
    const int plane = i / kHW4;            // magic-mul div
    const int c = plane & (kC - 1);        // C=256 pow2
    const int t = (plane >> 8) & (kT - 1); // T=8 pow2
    int off;
    bool valid;
    if (c < kFold)          { off =  kCHW4; valid = (t < kT - 1); }
    else if (c < 2 * kFold) { off = -kCHW4; valid = (t > 0); }
    else                    { off = 0;      valid = true; }
    v[j] = valid ? __builtin_nontemporal_load(&in[i + off]) : zero;
  }
}

__device__ __forceinline__ void store_chunk(const f32x4* v, int base,
                                            f32x4* __restrict__ out) {
#pragma unroll
  for (int j = 0; j < kUnroll; ++j)
    __builtin_nontemporal_store(v[j], &out[base + j * kBlk]);
}

__global__ __launch_bounds__(kBlk) void tsm_shift_kernel(
    const f32x4* __restrict__ in, f32x4* __restrict__ out) {
  f32x4 A[kUnroll], B[kUnroll];
  int base = blockIdx.x * kChunk + (int)threadIdx.x;
  load_chunk(A, base, in);
#pragma unroll
  for (int k = 0; k < kSteps; ++k) {
    f32x4* cur = (k & 1) ? B : A;   // static after unroll -> stays in registers
    f32x4* nxt = (k & 1) ? A : B;
    if (k + 1 < kSteps) load_chunk(nxt, base + kStride, in);
    store_chunk(cur, base, out);
    base += kStride;
  }
}

extern "C" void kernel_launch(void* const* d_in, const int* in_sizes, int n_in,
                              void* d_out, int out_size, void* d_ws, size_t ws_size,
                              hipStream_t stream) {
  const f32x4* x = (const f32x4*)d_in[0];
  f32x4* out = (f32x4*)d_out;
  tsm_shift_kernel<<<kGrid, kBlk, 0, stream>>>(x, out);
}